// Round 5
// baseline (342.857 us; speedup 1.0000x reference)
//
#include <hip/hip_runtime.h>

#define T_PRIOR 168
#define N_FEAT 11
#define DEC_FEAT 7
#define HID 64
#define T_DEC 48
#define BATCH 8192

typedef __attribute__((ext_vector_type(8))) short short8;
typedef __attribute__((ext_vector_type(4))) float f32x4;

#define MFMA __builtin_amdgcn_mfma_f32_16x16x32_bf16

__device__ __forceinline__ float sigm(float x) { return 1.0f / (1.0f + __expf(-x)); }
__device__ __forceinline__ float tanhfast(float x) { return 2.0f / (1.0f + __expf(-2.0f * x)) - 1.0f; }
__device__ __forceinline__ unsigned fbits(float f) { union { float f; unsigned u; } v; v.f = f; return v.u; }
__device__ __forceinline__ float bitsf(unsigned u) { union { unsigned u; float f; } v; v.u = u; return v.f; }
__device__ __forceinline__ unsigned short bf16rne(float f) {
    unsigned u = fbits(f);
    return (unsigned short)((u + 0x7fffu + ((u >> 16) & 1u)) >> 16);
}

__global__ __launch_bounds__(256) __attribute__((amdgpu_waves_per_eu(2)))
void gru_mfma(const float* __restrict__ prior, const float* __restrict__ teacher,
              const float* __restrict__ eWih, const float* __restrict__ eWhh,
              const float* __restrict__ eBih, const float* __restrict__ eBhh,
              const float* __restrict__ dWih, const float* __restrict__ dWhh,
              const float* __restrict__ dBih, const float* __restrict__ dBhh,
              const float* __restrict__ fcW, const float* __restrict__ fcB,
              float* __restrict__ out)
{
    // block-shared h bounce: [parity][hi/lo][16 rows x 64 kappa] bf16, XOR-swizzled
    __shared__ __align__(16) unsigned short sH[2][2][1024];
    __shared__ __align__(16) float sPartial[2][4][16];   // [parity][wave][row]

    const int tid  = (int)threadIdx.x;
    const int lane = tid & 63;
    const int w    = tid >> 6;     // wave id = unit tile (0..3)
    const int c    = lane & 15;    // A row / B col / C col
    const int g    = lane >> 4;    // k-group
    const int row0 = (int)blockIdx.x * 16;

    // hoisted swizzled LDS byte offsets
    unsigned pubOff[4];
#pragma unroll
    for (int q = 0; q < 4; ++q) {
        int r = g * 4 + q;
        pubOff[q] = (unsigned)(r * 128) +
                    (((unsigned)(c * 8 + w * 2)) ^ (((unsigned)(r & 7)) << 4));
    }
    const unsigned swz = ((unsigned)(c & 7)) << 4;
    const unsigned rb0 = (unsigned)(c * 128) + (((unsigned)(g * 16)) ^ swz);
    const unsigned rb1 = (unsigned)(c * 128) + (((unsigned)(64 + g * 16)) ^ swz);

    // per-wave persistent fragments (unit tile w only)
    short8 BHH[3][2];   // [gate][kt] Whh^T B-frags, kappa-permuted
    short8 BIH[3];      // [gate]     Wih^T B-frags (K padded to 32)
    f32x4 bR4, bZ4, bI4, bH4;
    float wih4[3] = {0.0f, 0.0f, 0.0f};   // decoder: Wih[:,4] column (pred feature)

    auto loadPhase = [&](const float* Wih, const float* Whh,
                         const float* bih, const float* bhh, int kvalid) {
        const int rw_base = w * 16 + c;
#pragma unroll
        for (int gate = 0; gate < 3; ++gate) {
            const int rw = gate * 64 + rw_base;
            union { short8 v; unsigned short s[8]; } fi;
#pragma unroll
            for (int j = 0; j < 8; ++j) {
                int k = g * 8 + j;
                fi.s[j] = (k < kvalid) ? bf16rne(Wih[rw * kvalid + k]) : (unsigned short)0;
            }
            BIH[gate] = fi.v;
            if (kvalid == DEC_FEAT) wih4[gate] = Wih[rw * kvalid + 4];
#pragma unroll
            for (int kt = 0; kt < 2; ++kt) {
                union { short8 v; unsigned short s[8]; } fh;
#pragma unroll
                for (int j = 0; j < 8; ++j) {
                    int kap = kt * 32 + g * 8 + j;              // permuted k index
                    int unit = ((kap & 3) << 4) | (kap >> 2);   // unit(kappa)
                    fh.s[j] = bf16rne(Whh[rw * 64 + unit]);
                }
                BHH[gate][kt] = fh.v;
            }
        }
        const int un = w * 16 + c;
        float vR = bih[un] + bhh[un];
        float vZ = bih[64 + un] + bhh[64 + un];
        float vI = bih[128 + un];
        float vH = bhh[128 + un];
        bR4 = (f32x4){vR, vR, vR, vR};
        bZ4 = (f32x4){vZ, vZ, vZ, vZ};
        bI4 = (f32x4){vI, vI, vI, vI};
        bH4 = (f32x4){vH, vH, vH, vH};
    };

    // publish this wave's 16-unit slice of h (hi/lo split, kappa layout, swizzled)
    auto publish = [&](int p, const float (&h)[4]) {
#pragma unroll
        for (int q = 0; q < 4; ++q) {
            unsigned hb = fbits(h[q]) & 0xffff0000u;
            unsigned short hi = (unsigned short)(hb >> 16);
            unsigned short lo = (unsigned short)(fbits(h[q] - bitsf(hb)) >> 16);
            *(unsigned short*)((char*)&sH[p][0][0] + pubOff[q]) = hi;
            *(unsigned short*)((char*)&sH[p][1][0] + pubOff[q]) = lo;
        }
    };

    // split 8 floats (k = g*8+j) into hi/lo bf16 A-fragments
    auto packsplit = [&](const float (&xv)[8], short8& xh, short8& xl) {
        union { short8 v; unsigned wd[4]; } uh, ul;
#pragma unroll
        for (int pp = 0; pp < 4; ++pp) {
            float a = xv[2 * pp], b = xv[2 * pp + 1];
            unsigned ba = fbits(a), bb = fbits(b);
            unsigned ha = ba & 0xffff0000u, hbv = bb & 0xffff0000u;
            float la = a - bitsf(ha), lb = b - bitsf(hbv);
            uh.wd[pp] = (ba >> 16) | hbv;
            ul.wd[pp] = (fbits(la) >> 16) | (fbits(lb) & 0xffff0000u);
        }
        xh = uh.v; xl = ul.v;
    };

    // x-part MFMAs (bias as C-in) -> accX{R,Z,I}; issued one step ahead
    auto xpart = [&](short8 xh, short8 xl, f32x4& oR, f32x4& oZ, f32x4& oI) {
        f32x4 a = MFMA(xh, BIH[0], bR4, 0, 0, 0);
        oR = MFMA(xl, BIH[0], a, 0, 0, 0);
        a = MFMA(xh, BIH[1], bZ4, 0, 0, 0);
        oZ = MFMA(xl, BIH[1], a, 0, 0, 0);
        a = MFMA(xh, BIH[2], bI4, 0, 0, 0);
        oI = MFMA(xl, BIH[2], a, 0, 0, 0);
    };

    // hh part: two independent 2-deep chains (hi, lo) per gate + add
    auto hh3 = [&](int p, f32x4 cR, f32x4 cZ, f32x4& oR, f32x4& oZ, f32x4& oH) {
        short8 a0h = *(const short8*)((const char*)&sH[p][0][0] + rb0);
        short8 a1h = *(const short8*)((const char*)&sH[p][0][0] + rb1);
        short8 a0l = *(const short8*)((const char*)&sH[p][1][0] + rb0);
        short8 a1l = *(const short8*)((const char*)&sH[p][1][0] + rb1);
        const f32x4 z4 = (f32x4){0.0f, 0.0f, 0.0f, 0.0f};
        f32x4 tR = MFMA(a0h, BHH[0][0], cR, 0, 0, 0);
        f32x4 uR = MFMA(a0l, BHH[0][0], z4, 0, 0, 0);
        f32x4 tZ = MFMA(a0h, BHH[1][0], cZ, 0, 0, 0);
        f32x4 uZ = MFMA(a0l, BHH[1][0], z4, 0, 0, 0);
        f32x4 tH = MFMA(a0h, BHH[2][0], bH4, 0, 0, 0);
        f32x4 uH = MFMA(a0l, BHH[2][0], z4, 0, 0, 0);
        tR = MFMA(a1h, BHH[0][1], tR, 0, 0, 0);
        uR = MFMA(a1l, BHH[0][1], uR, 0, 0, 0);
        tZ = MFMA(a1h, BHH[1][1], tZ, 0, 0, 0);
        uZ = MFMA(a1l, BHH[1][1], uZ, 0, 0, 0);
        tH = MFMA(a1h, BHH[2][1], tH, 0, 0, 0);
        uH = MFMA(a1l, BHH[2][1], uH, 0, 0, 0);
        oR = tR + uR; oZ = tZ + uZ; oH = tH + uH;
    };

    auto gates = [&](f32x4 aR, f32x4 aZ, f32x4 aHN, f32x4 aIN, float (&h)[4]) {
#pragma unroll
        for (int q = 0; q < 4; ++q) {
            float rr = sigm(aR[q]);
            float zz = sigm(aZ[q]);
            float nn = tanhfast(fmaf(rr, aHN[q], aIN[q]));
            h[q] = nn + zz * (h[q] - nn);
        }
    };

    float h[4] = {0.0f, 0.0f, 0.0f, 0.0f};

    // ================= encoder =================
    loadPhase(eWih, eWhh, eBih, eBhh, N_FEAT);
    const float* prow = prior + (size_t)(row0 + c) * (T_PRIOR * N_FEAT);

    f32x4 aXR, aXZ, aXI;
    {
        float xc[8] = {0, 0, 0, 0, 0, 0, 0, 0};
        if (g == 0) {
#pragma unroll
            for (int j = 0; j < 8; ++j) xc[j] = prow[j];
        } else if (g == 1) {
#pragma unroll
            for (int j = 0; j < 3; ++j) xc[j] = prow[8 + j];
        }
        short8 xh, xl;
        packsplit(xc, xh, xl);
        xpart(xh, xl, aXR, aXZ, aXI);
    }

    for (int t = 0; t < T_PRIOR; ++t) {
        const int p = t & 1;
        publish(p, h);
        float xn[8] = {0, 0, 0, 0, 0, 0, 0, 0};
        if (t < T_PRIOR - 1) {               // prefetch next x
            if (g == 0) {
#pragma unroll
                for (int j = 0; j < 8; ++j) xn[j] = prow[(t + 1) * N_FEAT + j];
            } else if (g == 1) {
#pragma unroll
                for (int j = 0; j < 3; ++j) xn[j] = prow[(t + 1) * N_FEAT + 8 + j];
            }
        }
        __syncthreads();
        f32x4 accR, accZ, accH;
        hh3(p, aXR, aXZ, accR, accZ, accH);
        gates(accR, accZ, accH, aXI, h);
        if (t < T_PRIOR - 1) {               // pipeline x-part for step t+1
            short8 xh, xl;
            packsplit(xn, xh, xl);
            xpart(xh, xl, aXR, aXZ, aXI);
        }
    }

    // ================= decoder =================
    loadPhase(dWih, dWhh, dBih, dBhh, DEC_FEAT);
    const float fwc = fcW[w * 16 + c];
    const float fb  = fcB[0];
    const float* trow = teacher + (size_t)(row0 + c) * (T_DEC * DEC_FEAT);

    {
        // x0 = teacher[:,0,:] (feat4 = teacher value, not pred)
        float dc[8] = {0, 0, 0, 0, 0, 0, 0, 0};
        if (g == 0) {
#pragma unroll
            for (int j = 0; j < 7; ++j) dc[j] = trow[j];
        }
        short8 xh, xl;
        packsplit(dc, xh, xl);
        xpart(xh, xl, aXR, aXZ, aXI);
    }

    for (int i = 0; i < T_DEC; ++i) {
        const int p = i & 1;
        publish(p, h);
        float dn[8] = {0, 0, 0, 0, 0, 0, 0, 0};
        if (i < T_DEC - 1 && g == 0) {       // teacher part of x_{i+1}, feat4 zeroed
#pragma unroll
            for (int j = 0; j < 7; ++j) dn[j] = trow[(i + 1) * DEC_FEAT + j];
            dn[4] = 0.0f;
        }
        __syncthreads();

        f32x4 predv = (f32x4){0.0f, 0.0f, 0.0f, 0.0f};
        if (i > 0) {                         // total pred_{i-1}, rows g*4..g*4+3
            const int b = (i - 1) & 1;
            f32x4 p0 = *(const f32x4*)&sPartial[b][0][g * 4];
            f32x4 p1 = *(const f32x4*)&sPartial[b][1][g * 4];
            f32x4 p2 = *(const f32x4*)&sPartial[b][2][g * 4];
            f32x4 p3 = *(const f32x4*)&sPartial[b][3][g * 4];
            predv = p0 + p1 + p2 + p3 + (f32x4){fb, fb, fb, fb};
            if (w == 0 && c == 0) {
#pragma unroll
                for (int q = 0; q < 4; ++q)
                    out[(size_t)(row0 + g * 4 + q) * T_DEC + (i - 1)] = predv[q];
            }
        }

        f32x4 accR, accZ, accH;
        hh3(p, aXR, aXZ, accR, accZ, accH);
        f32x4 accI = aXI;
        if (i > 0) {                         // pred feature contribution (fp32)
            accR += predv * wih4[0];
            accZ += predv * wih4[1];
            accI += predv * wih4[2];
        }
        gates(accR, accZ, accH, accI, h);

        // fc partials over this wave's 16 units
#pragma unroll
        for (int q = 0; q < 4; ++q) {
            float v = h[q] * fwc;
            v += __shfl_xor(v, 1, 64);
            v += __shfl_xor(v, 2, 64);
            v += __shfl_xor(v, 4, 64);
            v += __shfl_xor(v, 8, 64);
            if (c == 0) sPartial[i & 1][w][g * 4 + q] = v;
        }
        if (i < T_DEC - 1) {                 // pipeline teacher x-part for i+1
            short8 xh, xl;
            packsplit(dn, xh, xl);
            xpart(xh, xl, aXR, aXZ, aXI);
        }
    }
    __syncthreads();
    {
        const int b = (T_DEC - 1) & 1;
        if (w == 0 && c == 0) {
            f32x4 p0 = *(const f32x4*)&sPartial[b][0][g * 4];
            f32x4 p1 = *(const f32x4*)&sPartial[b][1][g * 4];
            f32x4 p2 = *(const f32x4*)&sPartial[b][2][g * 4];
            f32x4 p3 = *(const f32x4*)&sPartial[b][3][g * 4];
            f32x4 predv = p0 + p1 + p2 + p3 + (f32x4){fb, fb, fb, fb};
#pragma unroll
            for (int q = 0; q < 4; ++q)
                out[(size_t)(row0 + g * 4 + q) * T_DEC + (T_DEC - 1)] = predv[q];
        }
    }
}

extern "C" void kernel_launch(void* const* d_in, const int* in_sizes, int n_in,
                              void* d_out, int out_size, void* d_ws, size_t ws_size,
                              hipStream_t stream)
{
    const float* prior   = (const float*)d_in[0];
    const float* teacher = (const float*)d_in[1];
    const float* eWih    = (const float*)d_in[2];
    const float* eWhh    = (const float*)d_in[3];
    const float* eBih    = (const float*)d_in[4];
    const float* eBhh    = (const float*)d_in[5];
    const float* dWih    = (const float*)d_in[6];
    const float* dWhh    = (const float*)d_in[7];
    const float* dBih    = (const float*)d_in[8];
    const float* dBhh    = (const float*)d_in[9];
    const float* fcW     = (const float*)d_in[10];
    const float* fcB     = (const float*)d_in[11];
    float* out = (float*)d_out;

    dim3 grid(BATCH / 16);    // 512 blocks x 4 waves = 2048 waves
    dim3 block(256);
    hipLaunchKernelGGL(gru_mfma, grid, block, 0, stream,
                       prior, teacher, eWih, eWhh, eBih, eBhh,
                       dWih, dWhh, dBih, dBhh, fcW, fcB, out);
}

// Round 6
// 304.226 us; speedup vs baseline: 1.1270x; 1.1270x over previous
//
#include <hip/hip_runtime.h>

#define T_PRIOR 168
#define N_FEAT 11
#define DEC_FEAT 7
#define HID 64
#define T_DEC 48
#define BATCH 8192
#define CH 8            // steps per staged chunk
#define XROW 100        // floats per row in sX (8 slots * 12 + 4 spare; 100%32=4 -> 2-way banks)
#define XSLOT 12        // floats per step slot (zero-padded)

typedef __attribute__((ext_vector_type(8))) short short8;
typedef __attribute__((ext_vector_type(4))) float f32x4;
typedef __attribute__((ext_vector_type(4))) int i32x4;

#define MFMA __builtin_amdgcn_mfma_f32_16x16x32_bf16

__device__ __forceinline__ float sigm(float x) { return 1.0f / (1.0f + __expf(-x)); }
__device__ __forceinline__ float tanhfast(float x) { return 2.0f / (1.0f + __expf(-2.0f * x)) - 1.0f; }
__device__ __forceinline__ unsigned fbits(float f) { union { float f; unsigned u; } v; v.f = f; return v.u; }
__device__ __forceinline__ float bitsf(unsigned u) { union { unsigned u; float f; } v; v.u = u; return v.f; }
__device__ __forceinline__ unsigned short bf16rne(float f) {
    unsigned u = fbits(f);
    return (unsigned short)((u + 0x7fffu + ((u >> 16) & 1u)) >> 16);
}
__device__ __forceinline__ short8 asShort8(i32x4 v) {
    union { i32x4 i; short8 s; } u; u.i = v; return u.s;
}

__global__ __launch_bounds__(256) __attribute__((amdgpu_waves_per_eu(2)))
void gru_mfma(const float* __restrict__ prior, const float* __restrict__ teacher,
              const float* __restrict__ eWih, const float* __restrict__ eWhh,
              const float* __restrict__ eBih, const float* __restrict__ eBhh,
              const float* __restrict__ dWih, const float* __restrict__ dWhh,
              const float* __restrict__ dBih, const float* __restrict__ dBhh,
              const float* __restrict__ fcW, const float* __restrict__ fcB,
              float* __restrict__ out)
{
    __shared__ __align__(16) unsigned short sH[2][2][1024];  // h bounce, parity x hi/lo, swizzled
    __shared__ __align__(16) float sX[2][16][XROW];          // staged inputs, chunk double-buffer
    __shared__ __align__(16) float sPartial[2][16][4];       // [parity][row][wave]

    const int tid  = (int)threadIdx.x;
    const int lane = tid & 63;
    const int w    = tid >> 6;     // wave id = unit tile (0..3)
    const int c    = lane & 15;    // A row / B col / C col (batch row)
    const int g    = lane >> 4;    // k-group
    const int row0 = (int)blockIdx.x * 16;

    // ---- hoisted LDS byte offsets ----
    unsigned pubOff[4];
#pragma unroll
    for (int q = 0; q < 4; ++q) {
        int r = g * 4 + q;
        pubOff[q] = (unsigned)(r * 128) +
                    (((unsigned)(c * 8 + w * 2)) ^ (((unsigned)(r & 7)) << 4));
    }
    const unsigned swz = ((unsigned)(c & 7)) << 4;
    const unsigned rb0 = (unsigned)(c * 128) + (((unsigned)(g * 16)) ^ swz);
    const unsigned rb1 = (unsigned)(c * 128) + (((unsigned)(64 + g * 16)) ^ swz);
    // x read offsets within a step slot (bytes). g=0 reads f0-3,f4-7; g>=1 reads f8-11 twice.
    const unsigned gOffA = (g == 0) ? 0u : 32u;
    const unsigned gOffB = (g == 0) ? 16u : 32u;
    const char* sXrowRd = (const char*)&sX[0][c][0];           // reader base (buf 0)
    // staging: lane -> (row, li)
    const int srow = tid >> 4, sli = tid & 15;
    char* sXrowWr = (char*)&sX[0][srow][0];
    int offE[6], offD[4];
#pragma unroll
    for (int n = 0; n < 6; ++n) { int k = sli + 16 * n; offE[n] = ((k / 11) * XSLOT + (k % 11)) * 4; }
#pragma unroll
    for (int n = 0; n < 4; ++n) { int k = sli + 16 * n; offD[n] = ((k / 7) * XSLOT + (k % 7)) * 4; }
    // pad-zero slots: encoder f=11 (128 entries); decoder f=7..11 (640 entries, 3 per lane)
    const int padE = (tid >> 3) * (XROW * 4) + (tid & 7) * (XSLOT * 4) + 44;
    int padD[3]; bool padDv[3];
#pragma unroll
    for (int it = 0; it < 3; ++it) {
        int e = tid + 256 * it;
        padDv[it] = e < 640;
        int rr = e / 40, rem = e - rr * 40;
        padD[it] = rr * (XROW * 4) + (rem / 5) * (XSLOT * 4) + (7 + rem % 5) * 4;
    }
    const float* gP = prior + (size_t)(row0 + srow) * (T_PRIOR * N_FEAT) + sli;
    const float* gT = teacher + (size_t)(row0 + srow) * (T_DEC * DEC_FEAT) + sli;
    const int BUFB = 16 * XROW * 4;   // chunk buffer stride in bytes

    // ---- per-wave persistent fragments ----
    short8 BHH[3][2];
    short8 BIH[3];
    f32x4 bR4, bZ4, bI4, bH4;

    auto loadPhase = [&](const float* Wih, const float* Whh,
                         const float* bih, const float* bhh, int kvalid) {
        const int rw_base = w * 16 + c;
#pragma unroll
        for (int gate = 0; gate < 3; ++gate) {
            const int rw = gate * 64 + rw_base;
            union { short8 v; unsigned short s[8]; } fi;
#pragma unroll
            for (int j = 0; j < 8; ++j) {
                int k = g * 8 + j;
                fi.s[j] = (k < kvalid) ? bf16rne(Wih[rw * kvalid + k]) : (unsigned short)0;
            }
            BIH[gate] = fi.v;
#pragma unroll
            for (int kt = 0; kt < 2; ++kt) {
                union { short8 v; unsigned short s[8]; } fh;
#pragma unroll
                for (int j = 0; j < 8; ++j) {
                    int kap = kt * 32 + g * 8 + j;
                    int unit = ((kap & 3) << 4) | (kap >> 2);
                    fh.s[j] = bf16rne(Whh[rw * 64 + unit]);
                }
                BHH[gate][kt] = fh.v;
            }
        }
        const int un = w * 16 + c;
        float vR = bih[un] + bhh[un];
        float vZ = bih[64 + un] + bhh[64 + un];
        float vI = bih[128 + un];
        float vH = bhh[128 + un];
        bR4 = (f32x4){vR, vR, vR, vR};
        bZ4 = (f32x4){vZ, vZ, vZ, vZ};
        bI4 = (f32x4){vI, vI, vI, vI};
        bH4 = (f32x4){vH, vH, vH, vH};
    };

    auto publish = [&](int p, const float (&h)[4]) {
#pragma unroll
        for (int q = 0; q < 4; ++q) {
            unsigned hb = fbits(h[q]) & 0xffff0000u;
            unsigned short hi = (unsigned short)(hb >> 16);
            unsigned short lo = (unsigned short)(fbits(h[q] - bitsf(hb)) >> 16);
            *(unsigned short*)((char*)&sH[p][0][0] + pubOff[q]) = hi;
            *(unsigned short*)((char*)&sH[p][1][0] + pubOff[q]) = lo;
        }
    };

    auto pairsplit = [&](float a, float b, unsigned& hw, unsigned& lw) {
        unsigned ba = fbits(a), bb = fbits(b);
        unsigned ha = ba & 0xffff0000u, hb = bb & 0xffff0000u;
        float la = a - bitsf(ha), lb = b - bitsf(hb);
        hw = (ba >> 16) | hb;
        lw = (fbits(la) >> 16) | (fbits(lb) & 0xffff0000u);
    };

    // read x for step slot from staged LDS and pack into hi/lo frags
    auto readXpack = [&](int buf, int slot, i32x4& XH, i32x4& XL, float& f4, float& f5) {
        const char* base = sXrowRd + buf * BUFB + slot * (XSLOT * 4);
        f32x4 v0 = *(const f32x4*)(base + gOffA);
        f32x4 v1 = *(const f32x4*)(base + gOffB);
        float xv[8] = {v0[0], v0[1], v0[2], v0[3], v1[0], v1[1], v1[2], v1[3]};
        f4 = xv[4]; f5 = xv[5];
        unsigned hw, lw;
#pragma unroll
        for (int pp = 0; pp < 4; ++pp) {
            pairsplit(xv[2 * pp], xv[2 * pp + 1], hw, lw);
            XH[pp] = (int)hw; XL[pp] = (int)lw;
        }
    };

    // one GRU step: fused 18-MFMA cluster (R4 structure) + gates
    auto gru_step = [&](int p, short8 xhi, short8 xlo, float (&h)[4]) {
        short8 a0h = *(const short8*)((const char*)&sH[p][0][0] + rb0);
        short8 a1h = *(const short8*)((const char*)&sH[p][0][0] + rb1);
        short8 a0l = *(const short8*)((const char*)&sH[p][1][0] + rb0);
        short8 a1l = *(const short8*)((const char*)&sH[p][1][0] + rb1);

        f32x4 accR = MFMA(a0h, BHH[0][0], bR4, 0, 0, 0);
        accR = MFMA(a0l, BHH[0][0], accR, 0, 0, 0);
        accR = MFMA(a1h, BHH[0][1], accR, 0, 0, 0);
        accR = MFMA(a1l, BHH[0][1], accR, 0, 0, 0);
        accR = MFMA(xhi, BIH[0], accR, 0, 0, 0);
        accR = MFMA(xlo, BIH[0], accR, 0, 0, 0);

        f32x4 accZ = MFMA(a0h, BHH[1][0], bZ4, 0, 0, 0);
        accZ = MFMA(a0l, BHH[1][0], accZ, 0, 0, 0);
        accZ = MFMA(a1h, BHH[1][1], accZ, 0, 0, 0);
        accZ = MFMA(a1l, BHH[1][1], accZ, 0, 0, 0);
        accZ = MFMA(xhi, BIH[1], accZ, 0, 0, 0);
        accZ = MFMA(xlo, BIH[1], accZ, 0, 0, 0);

        f32x4 accH = MFMA(a0h, BHH[2][0], bH4, 0, 0, 0);
        accH = MFMA(a0l, BHH[2][0], accH, 0, 0, 0);
        accH = MFMA(a1h, BHH[2][1], accH, 0, 0, 0);
        accH = MFMA(a1l, BHH[2][1], accH, 0, 0, 0);

        f32x4 accI = MFMA(xhi, BIH[2], bI4, 0, 0, 0);
        accI = MFMA(xlo, BIH[2], accI, 0, 0, 0);

#pragma unroll
        for (int q = 0; q < 4; ++q) {
            float rr = sigm(accR[q]);
            float zz = sigm(accZ[q]);
            float nn = tanhfast(fmaf(rr, accH[q], accI[q]));
            h[q] = nn + zz * (h[q] - nn);
        }
    };

    float h[4] = {0.0f, 0.0f, 0.0f, 0.0f};

    // ================= encoder =================
    loadPhase(eWih, eWhh, eBih, eBhh, N_FEAT);

    {   // prologue: stage chunk 0
        float stg[6];
#pragma unroll
        for (int n = 0; n < 5; ++n) stg[n] = gP[16 * n];
        stg[5] = (sli < 8) ? gP[80] : 0.0f;
        char* dst = sXrowWr;
#pragma unroll
        for (int n = 0; n < 5; ++n) *(float*)(dst + offE[n]) = stg[n];
        if (sli < 8) *(float*)(dst + offE[5]) = stg[5];
        if (tid < 128) *(float*)((char*)&sX[0][0][0] + padE) = 0.0f;
    }
    __syncthreads();

    i32x4 XH, XL; float f4d, f5d;
    readXpack(0, 0, XH, XL, f4d, f5d);

    for (int t = 0; t < T_PRIOR; ++t) {
        const int p = t & 1;
        publish(p, h);
        __syncthreads();
        const bool doStage = ((t & 7) == 0) && (t + CH < T_PRIOR);
        float stg[6];
        int cNext = (t >> 3) + 1;
        if (doStage) {                       // issue loads right after barrier (full-step cover)
            const float* s = gP + 88 * cNext;
#pragma unroll
            for (int n = 0; n < 5; ++n) stg[n] = s[16 * n];
            stg[5] = (sli < 8) ? s[80] : 0.0f;
        }
        gru_step(p, asShort8(XH), asShort8(XL), h);
        if (doStage) {                       // write staged chunk at step end
            char* dst = sXrowWr + (cNext & 1) * BUFB;
#pragma unroll
            for (int n = 0; n < 5; ++n) *(float*)(dst + offE[n]) = stg[n];
            if (sli < 8) *(float*)(dst + offE[5]) = stg[5];
            if (tid < 128) *(float*)((char*)&sX[0][0][0] + (cNext & 1) * BUFB + padE) = 0.0f;
        }
        if (t < T_PRIOR - 1)
            readXpack(((t + 1) >> 3) & 1, (t + 1) & 7, XH, XL, f4d, f5d);
    }

    // ================= decoder =================
    __syncthreads();   // protect sX reuse across phases
    loadPhase(dWih, dWhh, dBih, dBhh, DEC_FEAT);
    const float fwc = fcW[w * 16 + c];
    const float fb  = fcB[0];

    {   // prologue: stage decoder chunk 0
        float stg[4];
#pragma unroll
        for (int n = 0; n < 3; ++n) stg[n] = gT[16 * n];
        stg[3] = (sli < 8) ? gT[48] : 0.0f;
        char* dst = sXrowWr;
#pragma unroll
        for (int n = 0; n < 3; ++n) *(float*)(dst + offD[n]) = stg[n];
        if (sli < 8) *(float*)(dst + offD[3]) = stg[3];
#pragma unroll
        for (int it = 0; it < 3; ++it)
            if (padDv[it]) *(float*)((char*)&sX[0][0][0] + padD[it]) = 0.0f;
    }
    __syncthreads();
    readXpack(0, 0, XH, XL, f4d, f5d);       // x0 = teacher[:,0,:], f4 = teacher value

    for (int i = 0; i < T_DEC; ++i) {
        const int p = i & 1;
        publish(p, h);
        __syncthreads();
        const bool doStage = ((i & 7) == 0) && (i + CH < T_DEC);
        float stg[4];
        int cNext = (i >> 3) + 1;
        if (doStage) {
            const float* s = gT + 56 * cNext;
#pragma unroll
            for (int n = 0; n < 3; ++n) stg[n] = s[16 * n];
            stg[3] = (sli < 8) ? s[48] : 0.0f;
        }
        if (i > 0) {                          // pred_{i-1}: patch frag word 2 = (pred, f5)
            const int b = (i - 1) & 1;
            const f32x4 pv = *(const f32x4*)&sPartial[b][c][0];
            float predc = pv[0] + pv[1] + pv[2] + pv[3] + fb;
            unsigned hw, lw;
            pairsplit(predc, f5d, hw, lw);
            XH[2] = (int)hw; XL[2] = (int)lw;
            if (w == 0 && lane < 16)
                out[(size_t)(row0 + lane) * T_DEC + (i - 1)] = predc;
        }
        gru_step(p, asShort8(XH), asShort8(XL), h);

#pragma unroll
        for (int q = 0; q < 4; ++q) {         // fc partials over this wave's 16 units
            float v = h[q] * fwc;
            v += __shfl_xor(v, 1, 64);
            v += __shfl_xor(v, 2, 64);
            v += __shfl_xor(v, 4, 64);
            v += __shfl_xor(v, 8, 64);
            if (c == 0) sPartial[i & 1][g * 4 + q][w] = v;
        }
        if (doStage) {
            char* dst = sXrowWr + (cNext & 1) * BUFB;
#pragma unroll
            for (int n = 0; n < 3; ++n) *(float*)(dst + offD[n]) = stg[n];
            if (sli < 8) *(float*)(dst + offD[3]) = stg[3];
#pragma unroll
            for (int it = 0; it < 3; ++it)
                if (padDv[it]) *(float*)((char*)&sX[0][0][0] + (cNext & 1) * BUFB + padD[it]) = 0.0f;
        }
        if (i < T_DEC - 1)
            readXpack(((i + 1) >> 3) & 1, (i + 1) & 7, XH, XL, f4d, f5d);
    }
    __syncthreads();
    {   // final pred (i = 47)
        const f32x4 pv = *(const f32x4*)&sPartial[(T_DEC - 1) & 1][c][0];
        float predc = pv[0] + pv[1] + pv[2] + pv[3] + fb;
        if (w == 0 && lane < 16)
            out[(size_t)(row0 + lane) * T_DEC + (T_DEC - 1)] = predc;
    }
}

extern "C" void kernel_launch(void* const* d_in, const int* in_sizes, int n_in,
                              void* d_out, int out_size, void* d_ws, size_t ws_size,
                              hipStream_t stream)
{
    const float* prior   = (const float*)d_in[0];
    const float* teacher = (const float*)d_in[1];
    const float* eWih    = (const float*)d_in[2];
    const float* eWhh    = (const float*)d_in[3];
    const float* eBih    = (const float*)d_in[4];
    const float* eBhh    = (const float*)d_in[5];
    const float* dWih    = (const float*)d_in[6];
    const float* dWhh    = (const float*)d_in[7];
    const float* dBih    = (const float*)d_in[8];
    const float* dBhh    = (const float*)d_in[9];
    const float* fcW     = (const float*)d_in[10];
    const float* fcB     = (const float*)d_in[11];
    float* out = (float*)d_out;

    dim3 grid(BATCH / 16);    // 512 blocks x 4 waves
    dim3 block(256);
    hipLaunchKernelGGL(gru_mfma, grid, block, 0, stream,
                       prior, teacher, eWih, eWhh, eBih, eBhh,
                       dWih, dWhh, dBih, dBhh, fcW, fcB, out);
}

// Round 7
// 270.738 us; speedup vs baseline: 1.2664x; 1.1237x over previous
//
#include <hip/hip_runtime.h>

#define T_PRIOR 168
#define N_FEAT 11
#define DEC_FEAT 7
#define HID 64
#define T_DEC 48
#define BATCH 8192
#define XROW 100        // floats per row in sX (fixed stride; %32=4 -> 2-way banks)
#define XSLOT 12        // floats per step slot (features zero-padded)

typedef __attribute__((ext_vector_type(8))) short short8;
typedef __attribute__((ext_vector_type(4))) float f32x4;
typedef __attribute__((ext_vector_type(2))) float f32x2;
typedef __attribute__((ext_vector_type(4))) int i32x4;

#define MFMA __builtin_amdgcn_mfma_f32_16x16x32_bf16

__device__ __forceinline__ unsigned fbits(float f){union{float f;unsigned u;}v;v.f=f;return v.u;}
__device__ __forceinline__ float bitsf(unsigned u){union{unsigned u;float f;}v;v.u=u;return v.f;}
__device__ __forceinline__ unsigned short bf16rne(float f){
    unsigned u=fbits(f);
    return (unsigned short)((u+0x7fffu+((u>>16)&1u))>>16);
}
// raw v_rcp_f32 (1 ulp) -- avoids the ~10-op IEEE division expansion
__device__ __forceinline__ float sigm(float x){ return __builtin_amdgcn_rcpf(1.0f + __expf(-x)); }
__device__ __forceinline__ float tanhf_(float x){ return fmaf(2.0f, __builtin_amdgcn_rcpf(1.0f + __expf(-2.0f*x)), -1.0f); }
__device__ __forceinline__ short8 s8(i32x4 v){union{i32x4 i;short8 s;}u;u.i=v;return u.s;}

// pack pair (a,b) -> one dword of 2 bf16: hi-truncation words or lo-residual words
__device__ __forceinline__ int packsel(float a, float b, bool hiSel){
    unsigned ba=fbits(a), bb=fbits(b);
    unsigned hw = (ba>>16) | (bb & 0xffff0000u);
    float la = a - bitsf(ba & 0xffff0000u);
    float lb = b - bitsf(bb & 0xffff0000u);
    unsigned lw = (fbits(la)>>16) | (fbits(lb) & 0xffff0000u);
    return (int)(hiSel ? hw : lw);
}

__global__ __launch_bounds__(512) __attribute__((amdgpu_waves_per_eu(4)))
void gru_mfma(const float* __restrict__ prior, const float* __restrict__ teacher,
              const float* __restrict__ eWih, const float* __restrict__ eWhh,
              const float* __restrict__ eBih, const float* __restrict__ eBhh,
              const float* __restrict__ dWih, const float* __restrict__ dWhh,
              const float* __restrict__ dBih, const float* __restrict__ dBhh,
              const float* __restrict__ fcW, const float* __restrict__ fcB,
              float* __restrict__ out)
{
    __shared__ __align__(16) unsigned short sHhi[1024];   // [16 rows][64 kappa], swizzled
    __shared__ __align__(16) unsigned short sHlo[1024];
    __shared__ __align__(16) float sXch[2][4][4][128];    // [s][u][acc R,Z,H,I][lane*2]
    __shared__ __align__(16) float sX[2][16][XROW];       // staged inputs (chunk dbuf)
    __shared__ __align__(16) float sPartial[16][4];       // [row][u]

    const int tid  = (int)threadIdx.x;
    const int lane = tid & 63;
    const int w    = tid >> 6;                 // 0..7
    const int u    = w & 3;                    // unit tile
    const int sU   = __builtin_amdgcn_readfirstlane(w >> 2);   // K-half (wave-uniform)
    const int c    = lane & 15;                // batch row / B col
    const int g    = lane >> 4;                // k-group
    const int row0 = (int)blockIdx.x * 16;

    // ---- hoisted addresses ----
    const unsigned rb = (unsigned)(c*128) + (((unsigned)(sU*64 + g*16)) ^ (((unsigned)(c&7))<<4));
    unsigned pubOff[2];
#pragma unroll
    for (int q = 0; q < 2; ++q) {
        int r = g*4 + sU*2 + q;
        pubOff[q] = (unsigned)(r*128) + (((unsigned)(c*8 + u*2)) ^ (((unsigned)(r&7))<<4));
    }
    float* xch  = &sXch[sU][u][0][0];          // own write region
    float* xchP = &sXch[sU^1][u][0][0];        // partner read region
    const int voff0 = (g==1) ? 32 : ((g==2) ? 16 : 0);
    const int voff1 = (g==0) ? 16 : ((g==2) ? 32 : 0);
    const bool hs0 = (g <= 1);
    const bool hs1 = (g == 0);
    // staging (first 4 waves only)
    const int srow = (tid & 255) >> 4, sli = tid & 15;
    char* sXwr = (char*)&sX[0][srow][0];
    int offE[6], offD[4];
#pragma unroll
    for (int n = 0; n < 6; ++n) { int k = sli + 16*n; offE[n] = ((k/11)*XSLOT + (k%11))*4; }
#pragma unroll
    for (int n = 0; n < 4; ++n) { int k = sli + 16*n; offD[n] = ((k/7)*XSLOT + (k%7))*4; }
    const int padE = ((tid&255) >> 3)*(XROW*4) + (tid & 7)*(XSLOT*4) + 44;
    int padD[3]; bool padDv[3];
#pragma unroll
    for (int it = 0; it < 3; ++it) {
        int e = (tid & 255) + 256*it;
        padDv[it] = e < 640;
        int rr = e/40, rem = e - rr*40;
        padD[it] = rr*(XROW*4) + (rem/5)*(XSLOT*4) + (7 + rem%5)*4;
    }
    const float* gP = prior   + (size_t)(row0 + srow)*(T_PRIOR*N_FEAT) + sli;
    const float* gT = teacher + (size_t)(row0 + srow)*(T_DEC*DEC_FEAT) + sli;
    const int BUFB = 16*XROW*4;
    const bool stager = (tid < 256);

    // ---- per-wave fragments ----
    short8 BHH[3];     // gates R,Z,H for this wave's kt = sU
    short8 BIH[2];     // s0: [I]; s1: [R, Z]   (K-packed: hi@k<kv, lo@12..12+kv)
    f32x4 bR4, bZ4, bH4, bI4;

    auto loadPhase = [&](const float* Wih, const float* Whh,
                         const float* bih, const float* bhh, int kvalid) {
        const int rwb = u*16 + c;
#pragma unroll
        for (int gate = 0; gate < 3; ++gate) {
            const int rw = gate*64 + rwb;
            union { short8 v; unsigned short s[8]; } fh;
#pragma unroll
            for (int j = 0; j < 8; ++j) {
                int kap = sU*32 + g*8 + j;
                int unit = ((kap & 3) << 4) | (kap >> 2);
                fh.s[j] = bf16rne(Whh[rw*64 + unit]);
            }
            BHH[gate] = fh.v;
        }
        // K-packed Wih B-frags
        auto mkBIH = [&](int gate) -> short8 {
            const int rw = gate*64 + rwb;
            union { short8 v; unsigned short s[8]; } fi;
#pragma unroll
            for (int j = 0; j < 8; ++j) {
                int k = g*8 + j;
                float wv = 0.0f;
                if (k < kvalid) wv = Wih[rw*kvalid + k];
                else if (k >= 12 && k < 12 + kvalid) wv = Wih[rw*kvalid + (k-12)];
                fi.s[j] = bf16rne(wv);
            }
            return fi.v;
        };
        if (sU == 0) { BIH[0] = mkBIH(2); }                 // i_n
        else         { BIH[0] = mkBIH(0); BIH[1] = mkBIH(1); }  // r, z
        const int un = u*16 + c;
        float vR = bih[un] + bhh[un];
        float vZ = bih[64+un] + bhh[64+un];
        float vI = bih[128+un];
        float vH = bhh[128+un];
        bR4 = (f32x4){vR,vR,vR,vR};
        bZ4 = (f32x4){vZ,vZ,vZ,vZ};
        bH4 = (f32x4){vH,vH,vH,vH};
        bI4 = (f32x4){vI,vI,vI,vI};
    };

    auto readXpack = [&](int buf, int slot, float pred, bool usePred) -> i32x4 {
        const char* base = (const char*)&sX[0][0][0] + buf*BUFB + c*(XROW*4) + slot*(XSLOT*4);
        f32x4 v0 = *(const f32x4*)(base + voff0);
        f32x4 v1 = *(const f32x4*)(base + voff1);
        if (usePred) {               // decoder feat4 = pred
            if (g == 0) v1[0] = pred;
            if (g == 2) v0[0] = pred;
        }
        i32x4 xp;
        xp[0] = packsel(v0[0], v0[1], hs0);
        xp[1] = packsel(v0[2], v0[3], hs0);
        xp[2] = packsel(v1[0], v1[1], hs1);
        xp[3] = packsel(v1[2], v1[3], hs1);
        return xp;
    };

    float h0 = 0.0f, h1 = 0.0f;      // this wave's 2 batch rows: g*4 + sU*2 + {0,1}
    float fwc = 0.0f, fb = 0.0f;

    // phase1: A-frag reads + MFMA partials + exchange-write
    f32x4 accR, accZ, accH, accI;
    auto phase1 = [&](i32x4 xp) {
        short8 aH = *(const short8*)((const char*)sHhi + rb);
        short8 aL = *(const short8*)((const char*)sHlo + rb);
        short8 xf = s8(xp);
        if (sU == 0) {
            accR = MFMA(aH, BHH[0], bR4, 0,0,0); accR = MFMA(aL, BHH[0], accR, 0,0,0);
            accZ = MFMA(aH, BHH[1], bZ4, 0,0,0); accZ = MFMA(aL, BHH[1], accZ, 0,0,0);
            accH = MFMA(aH, BHH[2], bH4, 0,0,0); accH = MFMA(aL, BHH[2], accH, 0,0,0);
            accI = MFMA(xf, BIH[0], bI4, 0,0,0);
            *(f32x2*)&xch[0*128 + lane*2] = (f32x2){accR[2], accR[3]};
            *(f32x2*)&xch[1*128 + lane*2] = (f32x2){accZ[2], accZ[3]};
            *(f32x2*)&xch[2*128 + lane*2] = (f32x2){accH[2], accH[3]};
            *(f32x2*)&xch[3*128 + lane*2] = (f32x2){accI[2], accI[3]};
        } else {
            const f32x4 z4 = (f32x4){0,0,0,0};
            accR = MFMA(aH, BHH[0], z4, 0,0,0); accR = MFMA(aL, BHH[0], accR, 0,0,0);
            accR = MFMA(xf, BIH[0], accR, 0,0,0);
            accZ = MFMA(aH, BHH[1], z4, 0,0,0); accZ = MFMA(aL, BHH[1], accZ, 0,0,0);
            accZ = MFMA(xf, BIH[1], accZ, 0,0,0);
            accH = MFMA(aH, BHH[2], z4, 0,0,0); accH = MFMA(aL, BHH[2], accH, 0,0,0);
            *(f32x2*)&xch[0*128 + lane*2] = (f32x2){accR[0], accR[1]};
            *(f32x2*)&xch[1*128 + lane*2] = (f32x2){accZ[0], accZ[1]};
            *(f32x2*)&xch[2*128 + lane*2] = (f32x2){accH[0], accH[1]};
        }
    };

    // phase2: combine partner partials, gates, h-update, publish
    auto phase2 = [&]() {
        float Rt0, Rt1, Zt0, Zt1, Ht0, Ht1, It0, It1;
        f32x2 pR = *(const f32x2*)&xchP[0*128 + lane*2];
        f32x2 pZ = *(const f32x2*)&xchP[1*128 + lane*2];
        f32x2 pH = *(const f32x2*)&xchP[2*128 + lane*2];
        if (sU == 0) {
            Rt0 = accR[0] + pR[0]; Rt1 = accR[1] + pR[1];
            Zt0 = accZ[0] + pZ[0]; Zt1 = accZ[1] + pZ[1];
            Ht0 = accH[0] + pH[0]; Ht1 = accH[1] + pH[1];
            It0 = accI[0];         It1 = accI[1];
        } else {
            f32x2 pI = *(const f32x2*)&xchP[3*128 + lane*2];
            Rt0 = accR[2] + pR[0]; Rt1 = accR[3] + pR[1];
            Zt0 = accZ[2] + pZ[0]; Zt1 = accZ[3] + pZ[1];
            Ht0 = accH[2] + pH[0]; Ht1 = accH[3] + pH[1];
            It0 = pI[0];           It1 = pI[1];
        }
        float rr0 = sigm(Rt0), zz0 = sigm(Zt0);
        float nn0 = tanhf_(fmaf(rr0, Ht0, It0));
        h0 = nn0 + zz0*(h0 - nn0);
        float rr1 = sigm(Rt1), zz1 = sigm(Zt1);
        float nn1 = tanhf_(fmaf(rr1, Ht1, It1));
        h1 = nn1 + zz1*(h1 - nn1);
        // publish (hi/lo split bf16, kappa layout, swizzled)
        unsigned b0 = fbits(h0) & 0xffff0000u;
        *(unsigned short*)((char*)sHhi + pubOff[0]) = (unsigned short)(b0 >> 16);
        *(unsigned short*)((char*)sHlo + pubOff[0]) = (unsigned short)(fbits(h0 - bitsf(b0)) >> 16);
        unsigned b1 = fbits(h1) & 0xffff0000u;
        *(unsigned short*)((char*)sHhi + pubOff[1]) = (unsigned short)(b1 >> 16);
        *(unsigned short*)((char*)sHlo + pubOff[1]) = (unsigned short)(fbits(h1 - bitsf(b1)) >> 16);
    };

    // ================= prologue =================
    if (tid < 512) { ((unsigned*)sHhi)[tid] = 0u; ((unsigned*)sHlo)[tid] = 0u; }  // h0 = 0
    loadPhase(eWih, eWhh, eBih, eBhh, N_FEAT);
    if (stager) {   // stage encoder chunk 0
        float stg[6];
#pragma unroll
        for (int n = 0; n < 5; ++n) stg[n] = gP[16*n];
        stg[5] = (sli < 8) ? gP[80] : 0.0f;
#pragma unroll
        for (int n = 0; n < 5; ++n) *(float*)(sXwr + offE[n]) = stg[n];
        if (sli < 8) *(float*)(sXwr + offE[5]) = stg[5];
        if ((tid & 255) < 128) *(float*)((char*)&sX[0][0][0] + padE) = 0.0f;
    }

    // ================= encoder =================
    for (int t = 0; t < T_PRIOR; ++t) {
        __syncthreads();   // barrier1: sH(t), sX chunk, xch free
        const bool doStage = ((t & 7) == 0) && (t + 8 < T_PRIOR) && stager;
        const int cNext = (t >> 3) + 1;
        float stg[6];
        if (doStage) {
            const float* sp = gP + 88*cNext;
#pragma unroll
            for (int n = 0; n < 5; ++n) stg[n] = sp[16*n];
            stg[5] = (sli < 8) ? sp[80] : 0.0f;
        }
        i32x4 xp = readXpack((t >> 3) & 1, t & 7, 0.0f, false);
        phase1(xp);
        __syncthreads();   // barrier2: xch ready, sH reads done
        phase2();
        if (doStage) {
            char* dst = sXwr + (cNext & 1)*BUFB;
#pragma unroll
            for (int n = 0; n < 5; ++n) *(float*)(dst + offE[n]) = stg[n];
            if (sli < 8) *(float*)(dst + offE[5]) = stg[5];
            if ((tid & 255) < 128) *(float*)((char*)&sX[0][0][0] + (cNext & 1)*BUFB + padE) = 0.0f;
        }
    }

    // ================= decoder setup =================
    loadPhase(dWih, dWhh, dBih, dBhh, DEC_FEAT);
    fwc = fcW[u*16 + c];
    fb  = fcB[0];
    if (stager) {   // stage decoder chunk 0 (safe: all waves past enc barrier2(167))
        float stg[4];
#pragma unroll
        for (int n = 0; n < 3; ++n) stg[n] = gT[16*n];
        stg[3] = (sli < 8) ? gT[48] : 0.0f;
#pragma unroll
        for (int n = 0; n < 3; ++n) *(float*)(sXwr + offD[n]) = stg[n];
        if (sli < 8) *(float*)(sXwr + offD[3]) = stg[3];
#pragma unroll
        for (int it = 0; it < 3; ++it)
            if (padDv[it]) *(float*)((char*)&sX[0][0][0] + padD[it]) = 0.0f;
    }

    // ================= decoder =================
    for (int i = 0; i < T_DEC; ++i) {
        __syncthreads();   // barrier1: sH, sPartial(i-1), sX ready
        const bool doStage = ((i & 7) == 0) && (i + 8 < T_DEC) && stager;
        const int cNext = (i >> 3) + 1;
        float stg[4];
        if (doStage) {
            const float* sp = gT + 56*cNext;
#pragma unroll
            for (int n = 0; n < 3; ++n) stg[n] = sp[16*n];
            stg[3] = (sli < 8) ? sp[48] : 0.0f;
        }
        float pred = 0.0f;
        if (i > 0) {
            f32x4 pp = *(const f32x4*)&sPartial[c][0];
            pred = pp[0] + pp[1] + pp[2] + pp[3] + fb;
            if (w == 0 && g == 0)
                out[(size_t)(row0 + c)*T_DEC + (i - 1)] = pred;
        }
        i32x4 xp = readXpack((i >> 3) & 1, i & 7, pred, i > 0);
        phase1(xp);
        __syncthreads();   // barrier2
        phase2();
        // fc partials over this wave's 16 units, 2 batch rows
#pragma unroll
        for (int q = 0; q < 2; ++q) {
            float v = (q == 0 ? h0 : h1) * fwc;
            v += __shfl_xor(v, 1, 64);
            v += __shfl_xor(v, 2, 64);
            v += __shfl_xor(v, 4, 64);
            v += __shfl_xor(v, 8, 64);
            if (c == 0) sPartial[g*4 + sU*2 + q][u] = v;
        }
        if (doStage) {
            char* dst = sXwr + (cNext & 1)*BUFB;
#pragma unroll
            for (int n = 0; n < 3; ++n) *(float*)(dst + offD[n]) = stg[n];
            if (sli < 8) *(float*)(dst + offD[3]) = stg[3];
#pragma unroll
            for (int it = 0; it < 3; ++it)
                if (padDv[it]) *(float*)((char*)&sX[0][0][0] + (cNext & 1)*BUFB + padD[it]) = 0.0f;
        }
    }
    __syncthreads();
    if (w == 0 && g == 0) {   // final pred (i = 47)
        f32x4 pp = *(const f32x4*)&sPartial[c][0];
        float pred = pp[0] + pp[1] + pp[2] + pp[3] + fb;
        out[(size_t)(row0 + c)*T_DEC + (T_DEC - 1)] = pred;
    }
}

extern "C" void kernel_launch(void* const* d_in, const int* in_sizes, int n_in,
                              void* d_out, int out_size, void* d_ws, size_t ws_size,
                              hipStream_t stream)
{
    const float* prior   = (const float*)d_in[0];
    const float* teacher = (const float*)d_in[1];
    const float* eWih    = (const float*)d_in[2];
    const float* eWhh    = (const float*)d_in[3];
    const float* eBih    = (const float*)d_in[4];
    const float* eBhh    = (const float*)d_in[5];
    const float* dWih    = (const float*)d_in[6];
    const float* dWhh    = (const float*)d_in[7];
    const float* dBih    = (const float*)d_in[8];
    const float* dBhh    = (const float*)d_in[9];
    const float* fcW     = (const float*)d_in[10];
    const float* fcB     = (const float*)d_in[11];
    float* out = (float*)d_out;

    dim3 grid(BATCH / 16);    // 512 blocks x 8 waves = 4096 waves (4/SIMD)
    dim3 block(512);
    hipLaunchKernelGGL(gru_mfma, grid, block, 0, stream,
                       prior, teacher, eWih, eWhh, eBih, eBhh,
                       dWih, dWhh, dBih, dBhh, fcW, fcB, out);
}

// Round 8
// 184.511 us; speedup vs baseline: 1.8582x; 1.4673x over previous
//
#include <hip/hip_runtime.h>

#define T_PRIOR 168
#define N_FEAT 11
#define DEC_FEAT 7
#define HID 64
#define T_DEC 48
#define BATCH 8192
#define XROW 132                 // uints per staged row: 8 slots x 16 words + 4 spare (132%32=4 -> bank stride 4c)
#define ROWB (XROW*4)            // 528 B
#define BUFB (16*ROWB)           // 8448 B per chunk buffer

typedef __attribute__((ext_vector_type(8))) short short8;
typedef __attribute__((ext_vector_type(4))) float f32x4;
typedef __attribute__((ext_vector_type(4))) int i32x4;
typedef __attribute__((ext_vector_type(4))) unsigned u32x4;

#define MFMA __builtin_amdgcn_mfma_f32_16x16x32_bf16

static __device__ __forceinline__ unsigned fbits(float f){union{float f;unsigned u;}v;v.f=f;return v.u;}
static __device__ __forceinline__ float bitsf(unsigned u){union{unsigned u;float f;}v;v.u=u;return v.f;}
static __device__ __forceinline__ unsigned short bf16rne(float f){
    unsigned x=fbits(f);
    return (unsigned short)((x+0x7fffu+((x>>16)&1u))>>16);
}
// v_rcp_f32-based gates (avoid IEEE div expansion)
static __device__ __forceinline__ float sigm(float x){ return __builtin_amdgcn_rcpf(1.0f + __expf(-x)); }
static __device__ __forceinline__ float tanhf_(float x){ return fmaf(2.0f, __builtin_amdgcn_rcpf(1.0f + __expf(-2.0f*x)), -1.0f); }
static __device__ __forceinline__ short8 s8(i32x4 v){union{i32x4 i;short8 s;}q;q.i=v;return q.s;}
// packed word: bf16-hi (truncated) in high 16 bits, bf16-lo (truncated residual) in low 16
static __device__ __forceinline__ unsigned packw(float x){
    unsigned hi = fbits(x) & 0xffff0000u;
    return hi | (fbits(x - bitsf(hi)) >> 16);
}

__global__ __launch_bounds__(256) __attribute__((amdgpu_waves_per_eu(2,2)))
void gru_mfma(const float* __restrict__ prior, const float* __restrict__ teacher,
              const float* __restrict__ eWih, const float* __restrict__ eWhh,
              const float* __restrict__ eBih, const float* __restrict__ eBhh,
              const float* __restrict__ dWih, const float* __restrict__ dWhh,
              const float* __restrict__ dBih, const float* __restrict__ dBhh,
              const float* __restrict__ fcW, const float* __restrict__ fcB,
              float* __restrict__ out)
{
    __shared__ __align__(16) unsigned short sHhi[2][1024];   // [parity][16 rows x 64 kappa], swizzled
    __shared__ __align__(16) unsigned short sHlo[2][1024];
    __shared__ __align__(16) unsigned sX[2*16*XROW];         // pre-packed (hi|lo) inputs, chunk dbuf
    __shared__ __align__(16) float sPartial[2][16][4];       // [parity][row][u]

    const int tid  = (int)threadIdx.x;
    const int lane = tid & 63;
    const int u    = tid >> 6;       // wave id = unit tile (full K per wave)
    const int c    = lane & 15;      // batch row / B col
    const int g    = lane >> 4;      // k-group
    const int row0 = (int)blockIdx.x * 16;

    // ---- sH fragment offsets (kappa layout, XOR-swizzled; proven in R4-R7) ----
    const unsigned cs = ((unsigned)(c & 7)) << 4;
    const unsigned rbA0 = (unsigned)(c*128) + (((unsigned)(g*16)) ^ cs);       // K 0..31
    const unsigned rbA1 = (unsigned)(c*128) + (((unsigned)(64 + g*16)) ^ cs);  // K 32..63
    unsigned pubOff[4];
#pragma unroll
    for (int q = 0; q < 4; ++q) {
        int r = g*4 + q;
        pubOff[q] = (unsigned)(r*128) + (((unsigned)(c*8 + u*2)) ^ (((unsigned)(r&7))<<4));
    }

    // ---- per-lane x-fragment tables (K-packing: k<kv -> hi f_k; 12<=k<12+kv -> lo f_{k-12}) ----
    const unsigned HI5 = 0x07060302u, LO5 = 0x05040100u;   // v_perm sels: hi-pair / lo-pair
    unsigned eA, eB, dA, dB, s01E, s23E, s01D, s23D;
    bool pA_, pB_;
    if (g == 0)      { eA=0;  eB=16; s01E=HI5; s23E=HI5; dA=0;  dB=16; s01D=HI5; s23D=HI5; pA_=false; pB_=true;  }
    else if (g == 1) { eA=32; eB=0;  s01E=HI5; s23E=LO5; dA=48; dB=0;  s01D=HI5; s23D=LO5; pA_=false; pB_=false; }
    else if (g == 2) { eA=16; eB=32; s01E=LO5; s23E=LO5; dA=16; dB=48; s01D=LO5; s23D=LO5; pA_=true;  pB_=false; }
    else             { eA=48; eB=48; s01E=HI5; s23E=HI5; dA=48; dB=48; s01D=HI5; s23D=HI5; pA_=false; pB_=false; }
    // offset 48 = slot words 12..15 = permanent zero pad
    const unsigned rdEA = (unsigned)(c*ROWB) + eA;
    const unsigned rdEB = (unsigned)(c*ROWB) + eB;
    const unsigned rdDA = (unsigned)(c*ROWB) + dA;
    const unsigned rdDB = (unsigned)(c*ROWB) + dB;
    char* sXB = (char*)sX;

    // ---- staging setup (all 256 threads) ----
    const int srow = tid >> 4, sli = tid & 15;
    char* sXwr = sXB + srow*ROWB;
    int offE[6], offD[4];
#pragma unroll
    for (int n = 0; n < 6; ++n) { int k = sli + 16*n; offE[n] = ((k/11)*16 + (k%11))*4; }
#pragma unroll
    for (int n = 0; n < 4; ++n) { int k = sli + 16*n; offD[n] = ((k/7)*16 + (k%7))*4; }
    const float* gP = prior   + (size_t)(row0 + srow)*(T_PRIOR*N_FEAT) + sli;
    const float* gT = teacher + (size_t)(row0 + srow)*(T_DEC*DEC_FEAT) + sli;

    // ---- per-wave weights (full K) ----
    short8 BHH[3][2], BIH[3];
    f32x4 bR4, bZ4, bH4, bI4;
    auto loadPhase = [&](const float* Wih, const float* Whh,
                         const float* bih, const float* bhh, int kvalid) {
        const int rwb = u*16 + c;
#pragma unroll
        for (int gate = 0; gate < 3; ++gate) {
            const int rw = gate*64 + rwb;
#pragma unroll
            for (int kt = 0; kt < 2; ++kt) {
                union { short8 v; unsigned short s[8]; } fh;
#pragma unroll
                for (int j = 0; j < 8; ++j) {
                    int kap = kt*32 + g*8 + j;
                    int unit = ((kap & 3) << 4) | (kap >> 2);   // kappa permutation
                    fh.s[j] = bf16rne(Whh[rw*64 + unit]);
                }
                BHH[gate][kt] = fh.v;
            }
            union { short8 v; unsigned short s[8]; } fi;
#pragma unroll
            for (int j = 0; j < 8; ++j) {
                int k = g*8 + j;
                float wv = 0.0f;
                if (k < kvalid) wv = Wih[rw*kvalid + k];
                else if (k >= 12 && k < 12 + kvalid) wv = Wih[rw*kvalid + (k-12)];
                fi.s[j] = bf16rne(wv);
            }
            BIH[gate] = fi.v;
        }
        const int un = u*16 + c;
        float vR = bih[un] + bhh[un];
        float vZ = bih[64+un] + bhh[64+un];
        float vI = bih[128+un];
        float vH = bhh[128+un];
        bR4 = (f32x4){vR,vR,vR,vR};
        bZ4 = (f32x4){vZ,vZ,vZ,vZ};
        bH4 = (f32x4){vH,vH,vH,vH};
        bI4 = (f32x4){vI,vI,vI,vI};
    };

    float h[4] = {0.0f, 0.0f, 0.0f, 0.0f};

    // one GRU step: read h(p) frags, 15 MFMA, gates, publish h into p^1
    auto gru_step = [&](int p, short8 xf) {
        const char* hb = (const char*)&sHhi[p][0];
        const char* lb = (const char*)&sHlo[p][0];
        short8 aH0 = *(const short8*)(hb + rbA0);
        short8 aH1 = *(const short8*)(hb + rbA1);
        short8 aL0 = *(const short8*)(lb + rbA0);
        short8 aL1 = *(const short8*)(lb + rbA1);

        f32x4 R = MFMA(aH0, BHH[0][0], bR4, 0,0,0);
        R = MFMA(aL0, BHH[0][0], R, 0,0,0);
        R = MFMA(aH1, BHH[0][1], R, 0,0,0);
        R = MFMA(aL1, BHH[0][1], R, 0,0,0);
        R = MFMA(xf,  BIH[0],    R, 0,0,0);
        f32x4 Z = MFMA(aH0, BHH[1][0], bZ4, 0,0,0);
        Z = MFMA(aL0, BHH[1][0], Z, 0,0,0);
        Z = MFMA(aH1, BHH[1][1], Z, 0,0,0);
        Z = MFMA(aL1, BHH[1][1], Z, 0,0,0);
        Z = MFMA(xf,  BIH[1],    Z, 0,0,0);
        f32x4 Hh = MFMA(aH0, BHH[2][0], bH4, 0,0,0);
        Hh = MFMA(aL0, BHH[2][0], Hh, 0,0,0);
        Hh = MFMA(aH1, BHH[2][1], Hh, 0,0,0);
        Hh = MFMA(aL1, BHH[2][1], Hh, 0,0,0);
        f32x4 I = MFMA(xf, BIH[2], bI4, 0,0,0);

        char* hw = (char*)&sHhi[p^1][0];
        char* lw = (char*)&sHlo[p^1][0];
#pragma unroll
        for (int q = 0; q < 4; ++q) {
            float rr = sigm(R[q]);
            float zz = sigm(Z[q]);
            float nn = tanhf_(fmaf(rr, Hh[q], I[q]));
            float hq = nn + zz*(h[q] - nn);
            h[q] = hq;
            unsigned hb2 = fbits(hq) & 0xffff0000u;
            *(unsigned short*)(hw + pubOff[q]) = (unsigned short)(hb2 >> 16);
            *(unsigned short*)(lw + pubOff[q]) = (unsigned short)(fbits(hq - bitsf(hb2)) >> 16);
        }
    };

    auto readXE2 = [&](unsigned bo, int sb) -> short8 {
        u32x4 A = *(const u32x4*)(sXB + (bo + rdEA + (unsigned)sb));
        u32x4 B = *(const u32x4*)(sXB + (bo + rdEB + (unsigned)sb));
        i32x4 f;
        f[0] = (int)__builtin_amdgcn_perm(A[1], A[0], s01E);
        f[1] = (int)__builtin_amdgcn_perm(A[3], A[2], s01E);
        f[2] = (int)__builtin_amdgcn_perm(B[1], B[0], s23E);
        f[3] = (int)__builtin_amdgcn_perm(B[3], B[2], s23E);
        return s8(f);
    };
    auto readXD2 = [&](unsigned bo, int sb, unsigned pw, bool dopatch) -> short8 {
        u32x4 A = *(const u32x4*)(sXB + (bo + rdDA + (unsigned)sb));
        u32x4 B = *(const u32x4*)(sXB + (bo + rdDB + (unsigned)sb));
        if (dopatch) {             // pred into feature 4 (hi+lo via packed word)
            if (pA_) A[0] = pw;
            if (pB_) B[0] = pw;
        }
        i32x4 f;
        f[0] = (int)__builtin_amdgcn_perm(A[1], A[0], s01D);
        f[1] = (int)__builtin_amdgcn_perm(A[3], A[2], s01D);
        f[2] = (int)__builtin_amdgcn_perm(B[1], B[0], s23D);
        f[3] = (int)__builtin_amdgcn_perm(B[3], B[2], s23D);
        return s8(f);
    };

    // ---------------- prologue ----------------
    {   // h0 = 0 into parity-0 buffers
        unsigned* z0 = (unsigned*)&sHhi[0][0];
        unsigned* z1 = (unsigned*)&sHlo[0][0];
#pragma unroll
        for (int it = 0; it < 2; ++it) { z0[tid + 256*it] = 0u; z1[tid + 256*it] = 0u; }
    }
    // zero slot words 11..15 (encoder f11 pad + permanent zero block), both buffers
#pragma unroll
    for (int it = 0; it < 5; ++it) {
        int e = tid + 256*it;
        int b = e / 640, r = (e - b*640) / 40, rem = e % 40;
        int slot = rem / 5, wd = 11 + rem % 5;
        sX[b*(16*XROW) + r*XROW + slot*16 + wd] = 0u;
    }
    loadPhase(eWih, eWhh, eBih, eBhh, N_FEAT);
    {   // stage encoder chunk 0 (pre-packed)
        float sv[6];
#pragma unroll
        for (int n = 0; n < 5; ++n) sv[n] = gP[16*n];
        sv[5] = (sli < 8) ? gP[80] : 0.0f;
#pragma unroll
        for (int n = 0; n < 5; ++n) *(unsigned*)(sXwr + offE[n]) = packw(sv[n]);
        if (sli < 8) *(unsigned*)(sXwr + offE[5]) = packw(sv[5]);
    }

    // ---------------- encoder: 21 chunks x 8 steps ----------------
    for (int ch = 0; ch < 21; ++ch) {
        const unsigned bo  = (unsigned)((ch & 1) * BUFB);
        const unsigned wbo = (unsigned)(((ch + 1) & 1) * BUFB);
        const bool st = (ch < 20);
        float sv[6];
#pragma unroll
        for (int s = 0; s < 8; ++s) {
            __syncthreads();
            if (s == 0 && st) {              // issue next-chunk loads (full-chunk latency cover)
                const float* sp = gP + 88*(ch+1);
#pragma unroll
                for (int n = 0; n < 5; ++n) sv[n] = sp[16*n];
                sv[5] = (sli < 8) ? sp[80] : 0.0f;
            }
            short8 xf = readXE2(bo, s*64);
            gru_step(s & 1, xf);
            if (s == 0 && st) {              // write to the other buffer (disjoint, no extra barrier)
#pragma unroll
                for (int n = 0; n < 5; ++n) *(unsigned*)(sXwr + wbo + offE[n]) = packw(sv[n]);
                if (sli < 8) *(unsigned*)(sXwr + wbo + offE[5]) = packw(sv[5]);
            }
        }
    }

    // ---------------- decoder setup ----------------
    __syncthreads();   // all encoder sX reads done before pad rewrites
    loadPhase(dWih, dWhh, dBih, dBhh, DEC_FEAT);
    const float fwc = fcW[u*16 + c];
    const float fb  = fcB[0];
#pragma unroll
    for (int it = 0; it < 4; ++it) {         // zero decoder pad words 7..10, both buffers
        int e = tid + 256*it;
        int b = e / 512, r = (e - b*512) / 32, rem = e % 32;
        int slot = rem / 4, wd = 7 + (rem & 3);
        sX[b*(16*XROW) + r*XROW + slot*16 + wd] = 0u;
    }
    {   // stage decoder chunk 0
        float sv[4];
#pragma unroll
        for (int n = 0; n < 3; ++n) sv[n] = gT[16*n];
        sv[3] = (sli < 8) ? gT[48] : 0.0f;
#pragma unroll
        for (int n = 0; n < 3; ++n) *(unsigned*)(sXwr + offD[n]) = packw(sv[n]);
        if (sli < 8) *(unsigned*)(sXwr + offD[3]) = packw(sv[3]);
    }

    // ---------------- decoder: 6 chunks x 8 steps ----------------
    for (int ch = 0; ch < 6; ++ch) {
        const unsigned bo  = (unsigned)((ch & 1) * BUFB);
        const unsigned wbo = (unsigned)(((ch + 1) & 1) * BUFB);
        const bool st = (ch < 5);
        float sv[4];
#pragma unroll
        for (int s = 0; s < 8; ++s) {
            const int i = ch*8 + s;
            __syncthreads();
            if (s == 0 && st) {
                const float* sp = gT + 56*(ch+1);
#pragma unroll
                for (int n = 0; n < 3; ++n) sv[n] = sp[16*n];
                sv[3] = (sli < 8) ? sp[48] : 0.0f;
            }
            unsigned pw = 0u;
            const bool hasPred = (s > 0) || (ch > 0);
            if (hasPred) {                    // pred_{i-1} from parity (s&1)^1 partials
                f32x4 pp = *(const f32x4*)&sPartial[(s & 1) ^ 1][c][0];
                float pred = pp[0] + pp[1] + pp[2] + pp[3] + fb;
                pw = packw(pred);
                if (u == 0 && g == 0)
                    out[(size_t)(row0 + c)*T_DEC + (i - 1)] = pred;
            }
            short8 xf = readXD2(bo, s*64, pw, hasPred);
            gru_step(s & 1, xf);
            // fc partials over this wave's 16 units
#pragma unroll
            for (int q = 0; q < 4; ++q) {
                float v = h[q] * fwc;
                v += __shfl_xor(v, 1, 64);
                v += __shfl_xor(v, 2, 64);
                v += __shfl_xor(v, 4, 64);
                v += __shfl_xor(v, 8, 64);
                if (c == 0) sPartial[s & 1][g*4 + q][u] = v;
            }
            if (s == 0 && st) {
#pragma unroll
                for (int n = 0; n < 3; ++n) *(unsigned*)(sXwr + wbo + offD[n]) = packw(sv[n]);
                if (sli < 8) *(unsigned*)(sXwr + wbo + offD[3]) = packw(sv[3]);
            }
        }
    }
    __syncthreads();
    if (u == 0 && g == 0) {   // final pred (i = 47, parity 1)
        f32x4 pp = *(const f32x4*)&sPartial[1][c][0];
        float pred = pp[0] + pp[1] + pp[2] + pp[3] + fb;
        out[(size_t)(row0 + c)*T_DEC + (T_DEC - 1)] = pred;
    }
}

extern "C" void kernel_launch(void* const* d_in, const int* in_sizes, int n_in,
                              void* d_out, int out_size, void* d_ws, size_t ws_size,
                              hipStream_t stream)
{
    const float* prior   = (const float*)d_in[0];
    const float* teacher = (const float*)d_in[1];
    const float* eWih    = (const float*)d_in[2];
    const float* eWhh    = (const float*)d_in[3];
    const float* eBih    = (const float*)d_in[4];
    const float* eBhh    = (const float*)d_in[5];
    const float* dWih    = (const float*)d_in[6];
    const float* dWhh    = (const float*)d_in[7];
    const float* dBih    = (const float*)d_in[8];
    const float* dBhh    = (const float*)d_in[9];
    const float* fcW     = (const float*)d_in[10];
    const float* fcB     = (const float*)d_in[11];
    float* out = (float*)d_out;

    dim3 grid(BATCH / 16);    // 512 blocks x 4 waves (full-K per wave, 1 barrier/step)
    dim3 block(256);
    hipLaunchKernelGGL(gru_mfma, grid, block, 0, stream,
                       prior, teacher, eWih, eWhh, eBih, eBhh,
                       dWih, dWhh, dBih, dBhh, fcW, fcB, out);
}